// Round 10
// baseline (363.281 us; speedup 1.0000x reference)
//
#include <hip/hip_runtime.h>
#include <stdint.h>

typedef unsigned short u16;
typedef __attribute__((ext_vector_type(4))) float f32x4;
typedef __attribute__((ext_vector_type(8))) __bf16 bf16x8;
typedef __attribute__((ext_vector_type(4))) u16 u16x4;
typedef __attribute__((ext_vector_type(8))) u16 u16x8;

#define T_SEQ 2048
#define NB 4
#define NH 16
#define NKV 4
#define HDIM 128
#define PSTR 72

__device__ __forceinline__ u16 f2bf(float f) {
  __bf16 h = (__bf16)f;
  return __builtin_bit_cast(u16, h);
}
__device__ __forceinline__ float bf2f(u16 u) {
  union { uint32_t u; float f; } v; v.u = ((uint32_t)u) << 16;
  return v.f;
}
__device__ __forceinline__ void gload16(const void* g, void* l) {
  __builtin_amdgcn_global_load_lds((const __attribute__((address_space(1))) void*)g,
                                   (__attribute__((address_space(3))) void*)l, 16, 0, 0);
}
__device__ __forceinline__ f32x4 mfma16(bf16x8 a, bf16x8 b, f32x4 c) {
  return __builtin_amdgcn_mfma_f32_16x16x32_bf16(a, b, c, 0, 0, 0);
}

// ---------------- fp32 -> bf16 convert (grid-stride) ----------------
__global__ __launch_bounds__(256) void cvt_bf16(const float* __restrict__ in,
                                                u16* __restrict__ out, int n) {
  int idx = blockIdx.x * 256 + threadIdx.x;
  int stride = gridDim.x * 256;
  for (int i = idx * 4; i < n; i += stride * 4) {
    f32x4 v = *(const f32x4*)(in + i);
    u16x4 o;
    o[0] = f2bf(v[0]); o[1] = f2bf(v[1]); o[2] = f2bf(v[2]); o[3] = f2bf(v[3]);
    *(u16x4*)(out + i) = o;
  }
}

// ---- 256x256 bf16 GEMM, 4-phase counted-vmcnt pipeline (T3+T4) ----
// 512 thr (8 waves 2Mx4N), per-wave 128x64, BK=64 split into K-halves [256][32].
// LDS: AH/BH[parity][khalf][256*32] = 128 KiB total, double-buffered by K-tile
// parity. Staging order per tile t (issued during t, for t+1):
//   A-KH0, B-KH0, A-KH1, B-KH1  (one half per sub-phase, 2 gloads/thread each)
// Waits: vmcnt(4) before each K-half's frag reads (2 halves in flight), never 0
// in steady state; barrier after wait publishes all waves' loads. 2 barriers
// per 64 MFMA. Swizzle (R5-verified 0-conflict): chunk cc ^ ((row>>1)&3),
// pre-swizzled global source + linear LDS dest + swizzled read (rule #21).
// Bt is (N,K) row-major. MODE 0: scatter q/k/v bf16. MODE 1: fp32 C.
template <int MODE>
__global__ __launch_bounds__(512, 2) void gemm256p4(const u16* __restrict__ A,
                                                    const u16* __restrict__ Bt,
                                                    u16* __restrict__ q_o, u16* __restrict__ k_o,
                                                    u16* __restrict__ v_o, float* __restrict__ f_o,
                                                    int K, int ntn, int cpx) {
  __shared__ __align__(16) u16 AH[2][2][256 * 32];
  __shared__ __align__(16) u16 BH[2][2][256 * 32];
  const int tid = threadIdx.x;
  const int l = tid & 63, w = tid >> 6;
  const int l16 = l & 15, g16 = l >> 4;
  const int wr = w >> 2, wc = w & 3;  // 2 (M) x 4 (N) waves

  // XCD-bijective block swizzle (grid % 8 == 0)
  const int oid = blockIdx.x;
  const int wid = (oid & 7) * cpx + (oid >> 3);
  const int m0 = (wid / ntn) * 256, n0 = (wid % ntn) * 256;

  f32x4 acc[8][4] = {};  // [rh*4 + row-frag][col-frag]

  // staging: thread covers rows r0=tid>>2 and r1=r0+128, chunk col cc=tid&3.
  // swizzled source chunk sc = cc ^ ((r>>1)&3)  (same for r0 and r0+128).
  const int r0 = tid >> 2, cc = tid & 3;
  const int sc = cc ^ ((r0 >> 1) & 3);
  const u16* pA0 = A + (size_t)(m0 + r0) * K + sc * 8;
  const u16* pA1 = A + (size_t)(m0 + r0 + 128) * K + sc * 8;
  const u16* pB0 = Bt + (size_t)(n0 + r0) * K + sc * 8;
  const u16* pB1 = Bt + (size_t)(n0 + r0 + 128) * K + sc * 8;
  const int wb = w * 1024;  // per-wave LDS byte base (lane*16 implicit)

#define STG_A(par, kh, ko)                                        \
  {                                                               \
    char* d = (char*)&AH[par][kh][0] + wb;                        \
    gload16(pA0 + (ko), d);                                       \
    gload16(pA1 + (ko), d + 8192);                                \
  }
#define STG_B(par, kh, ko)                                        \
  {                                                               \
    char* d = (char*)&BH[par][kh][0] + wb;                        \
    gload16(pB0 + (ko), d);                                       \
    gload16(pB1 + (ko), d + 8192);                                \
  }
#define RD_B(par, kh)                                             \
  _Pragma("unroll")                                               \
  for (int nf = 0; nf < 4; ++nf) {                                \
    int brow = wc * 64 + nf * 16 + l16;                           \
    bfr[nf] = *(const bf16x8*)&BH[par][kh][brow * 32 +            \
                               ((g16 ^ ((brow >> 1) & 3)) * 8)];  \
  }
#define RD_A(par, kh, rh)                                         \
  _Pragma("unroll")                                               \
  for (int f = 0; f < 4; ++f) {                                   \
    int arow = wr * 128 + (rh) * 64 + f * 16 + l16;               \
    af[f] = *(const bf16x8*)&AH[par][kh][arow * 32 +              \
                             ((g16 ^ ((arow >> 1) & 3)) * 8)];    \
  }
#define MM(rh)                                                    \
  __builtin_amdgcn_s_setprio(1);                                  \
  _Pragma("unroll")                                               \
  for (int f = 0; f < 4; ++f)                                     \
    _Pragma("unroll")                                             \
    for (int nf = 0; nf < 4; ++nf)                                \
      acc[(rh) * 4 + f][nf] = mfma16(af[f], bfr[nf],              \
                                     acc[(rh) * 4 + f][nf]);      \
  __builtin_amdgcn_s_setprio(0);

  const int ntk = K >> 6;
  // prologue: tile 0's four halves (8 gloads in flight)
  STG_A(0, 0, 0); STG_B(0, 0, 0); STG_A(0, 1, 32); STG_B(0, 1, 32);

  for (int t = 0; t < ntk; ++t) {
    const int p = t & 1;
    const bool st = (t + 1 < ntk);
    const int ko = (t + 1) << 6;
    bf16x8 bfr[4], af[4];

    // ---- K-half 0 ----
    asm volatile("s_waitcnt vmcnt(4)" ::: "memory");  // KH0(t) landed (KH1 in flight)
    __builtin_amdgcn_s_barrier();
    RD_B(p, 0);
    RD_A(p, 0, 0);
    if (st) STG_A(p ^ 1, 0, ko);     // H+0 of tile t+1
    MM(0);
    RD_A(p, 0, 1);
    if (st) STG_B(p ^ 1, 0, ko);     // H+1
    MM(1);

    // ---- K-half 1 ----
    if (st) {
      asm volatile("s_waitcnt vmcnt(4)" ::: "memory");  // KH1(t) landed (t+1 KH0 in flight)
    } else {
      asm volatile("s_waitcnt vmcnt(0)" ::: "memory");  // nothing younger issued
    }
    __builtin_amdgcn_s_barrier();
    RD_B(p, 1);
    RD_A(p, 1, 0);
    if (st) STG_A(p ^ 1, 1, ko + 32);  // H+2
    MM(0);
    RD_A(p, 1, 1);
    if (st) STG_B(p ^ 1, 1, ko + 32);  // H+3
    MM(1);
  }
#undef STG_A
#undef STG_B
#undef RD_A
#undef RD_B
#undef MM

  // epilogue: D[row = g16*4 + rr][col = l16] per fragment
#pragma unroll
  for (int rf = 0; rf < 8; ++rf) {
#pragma unroll
    for (int rr = 0; rr < 4; ++rr) {
      int row = m0 + wr * 128 + rf * 16 + g16 * 4 + rr;
#pragma unroll
      for (int nf = 0; nf < 4; ++nf) {
        int n = n0 + wc * 64 + nf * 16 + l16;
        float val = acc[rf][nf][rr];
        if (MODE == 1) {
          f_o[(size_t)row * 2048 + n] = val;
        } else {
          int b = row >> 11, t = row & (T_SEQ - 1);
          u16 bv = f2bf(val);
          if (n < 2048) {
            int h = n >> 7, d = n & 127;
            q_o[((size_t)(b * NH + h) * T_SEQ + t) * HDIM + d] = bv;
          } else if (n < 2560) {
            int n2 = n - 2048; int h = n2 >> 7, d = n2 & 127;
            k_o[((size_t)(b * NKV + h) * T_SEQ + t) * HDIM + d] = bv;
          } else {
            int n2 = n - 2560; int h = n2 >> 7, d = n2 & 127;
            v_o[((size_t)(b * NKV + h) * T_SEQ + t) * HDIM + d] = bv;
          }
        }
      }
    }
  }
}

// ---------------- fused RMSNorm + RoPE (+ gain/scale fold), in-place ----------------
__global__ __launch_bounds__(256) void rmsrope(u16* __restrict__ buf,
                                               const float* __restrict__ gains,
                                               int nheads, float fold, int useGain) {
  const int w = threadIdx.x >> 6, l = threadIdx.x & 63;
  const int rid = blockIdx.x * 4 + w;
  const int t = rid & (T_SEQ - 1);
  const int h = (rid >> 11) % nheads;
  u16* p = buf + (size_t)rid * HDIM;
  float x1 = bf2f(p[l]), x2 = bf2f(p[l + 64]);
  float ss = x1 * x1 + x2 * x2;
#pragma unroll
  for (int m = 32; m; m >>= 1) ss += __shfl_xor(ss, m, 64);
  float rn = rsqrtf(ss * (1.0f / 128.0f) + 1.1920928955078125e-7f);
  float g = useGain ? gains[h] * fold : fold;
  float sc = rn * g;
  float inv = exp2f(-(float)l * (13.287712379549449f / 64.0f));
  float ang = (float)t * inv;
  float s, c;
  __sincosf(ang, &s, &c);
  float o1 = (x1 * c + x2 * s) * sc;
  float o2 = (x2 * c - x1 * s) * sc;
  p[l] = f2bf(o1);
  p[l + 64] = f2bf(o2);
}

// ---------------- V transpose: (B,NKV,T,128) -> (B,NKV,128,T) ----------------
__global__ __launch_bounds__(256) void vtrans(const u16* __restrict__ in,
                                              u16* __restrict__ out) {
  __shared__ u16 tileT[64][PSTR];
  const int tid = threadIdx.x;
  const int t0 = blockIdx.x * 64, d0 = blockIdx.y * 64, bg = blockIdx.z;
  const int row = tid >> 2, c0 = (tid & 3) * 16;
  const u16* src = in + ((size_t)bg * T_SEQ + t0 + row) * HDIM + d0 + c0;
  u16x8 a = *(const u16x8*)src;
  u16x8 bb = *(const u16x8*)(src + 8);
#pragma unroll
  for (int j = 0; j < 8; ++j) {
    tileT[c0 + j][row] = a[j];
    tileT[c0 + 8 + j][row] = bb[j];
  }
  __syncthreads();
  u16* dst = out + ((size_t)bg * HDIM + d0 + row) * T_SEQ + t0 + c0;
  *(u16x8*)dst = *(const u16x8*)&tileT[row][c0];
  *(u16x8*)(dst + 8) = *(const u16x8*)&tileT[row][c0 + 8];
}

// ---------------- flash GQA causal attention v3 (swapped QK^T, paired q-tiles) ----
__global__ __launch_bounds__(256) void attn_fwd3(const u16* __restrict__ qb,
                                                 const u16* __restrict__ kb,
                                                 const u16* __restrict__ vtb,
                                                 u16* __restrict__ yb,
                                                 const float* __restrict__ gains) {
  __shared__ __align__(16) u16 Ks[64 * 128];
  __shared__ __align__(16) u16 Vs[128 * 64];
  __shared__ __align__(16) u16 Ps[4][32 * PSTR];

  const int tid = threadIdx.x, l = tid & 63, w = tid >> 6;
  const int l16 = l & 15, g16 = l >> 4;

  const int oid = blockIdx.x + 8 * blockIdx.y;
  const int wid = (oid & 7) * 64 + (oid >> 3);
  const int pair = wid & 7, bh = wid >> 3;
  const int b = bh >> 4, h = bh & 15, gr = h >> 2;

  const float Mh = 16.33f * fabsf(gains[h]) + 0.5f;
  const u16* kbase = kb + (size_t)(b * NKV + gr) * T_SEQ * HDIM;
  const u16* vtbase = vtb + (size_t)(b * NKV + gr) * HDIM * T_SEQ;

  for (int phase = 0; phase < 2; ++phase) {
    const int qt = phase ? (15 - pair) : pair;
    const int q0 = qt * 128 + w * 32;
    const int qhi = q0 + 31;

    bf16x8 qf[2][4];
    const u16* qbase = qb + ((size_t)bh * T_SEQ + q0) * HDIM;
#pragma unroll
    for (int nf = 0; nf < 2; ++nf)
#pragma unroll
      for (int s = 0; s < 4; ++s)
        qf[nf][s] = *(const bf16x8*)(qbase + (size_t)(nf * 16 + l16) * HDIM + s * 32 + g16 * 8);

    f32x4 oacc[2][8] = {};
    float den[2] = {0.f, 0.f};
    const int ntile = 2 * qt + 2;

    for (int kt = 0; kt < ntile; ++kt) {
#pragma unroll
      for (int r = 0; r < 4; ++r) {
        int c = r * 256 + tid;
        int row = c >> 4, c16 = c & 15;
        int sc = c16 ^ (row & 7);
        gload16(kbase + ((size_t)(kt * 64 + row)) * HDIM + sc * 8,
                (char*)Ks + (r * 256 + w * 64) * 16);
      }
#pragma unroll
      for (int r = 0; r < 4; ++r) {
        int c = r * 256 + tid;
        int row = c >> 3, c8 = c & 7;
        int sc = c8 ^ (row & 7);
        gload16(vtbase + (size_t)row * T_SEQ + kt * 64 + sc * 8,
                (char*)Vs + (r * 256 + w * 64) * 16);
      }
      __syncthreads();

      if (kt * 64 <= qhi) {
        f32x4 sacc[4][2] = {};
        __builtin_amdgcn_s_setprio(1);
#pragma unroll
        for (int mt = 0; mt < 4; ++mt) {
          int key = mt * 16 + l16;
#pragma unroll
          for (int s = 0; s < 4; ++s) {
            bf16x8 kf = *(const bf16x8*)&Ks[key * 128 + ((s * 4 + g16) ^ (key & 7)) * 8];
#pragma unroll
            for (int nf = 0; nf < 2; ++nf)
              sacc[mt][nf] = mfma16(kf, qf[nf][s], sacc[mt][nf]);
          }
        }
        __builtin_amdgcn_s_setprio(0);

        const bool diagcross = (kt * 64 + 63 > q0);
#pragma unroll
        for (int mt = 0; mt < 4; ++mt) {
          int keyb = kt * 64 + mt * 16 + g16 * 4;
#pragma unroll
          for (int nf = 0; nf < 2; ++nf) {
            u16x4 p4;
#pragma unroll
            for (int r = 0; r < 4; ++r) {
              float pv = exp2f(sacc[mt][nf][r] - Mh);
              if (diagcross && (keyb + r > q0 + nf * 16 + l16)) pv = 0.f;
              den[nf] += pv;
              p4[r] = f2bf(pv);
            }
            *(u16x4*)&Ps[w][(nf * 16 + l16) * PSTR + mt * 16 + g16 * 4] = p4;
          }
        }

        __builtin_amdgcn_s_setprio(1);
#pragma unroll
        for (int ks = 0; ks < 2; ++ks) {
          bf16x8 pa[2];
#pragma unroll
          for (int mq = 0; mq < 2; ++mq)
            pa[mq] = *(const bf16x8*)&Ps[w][(mq * 16 + l16) * PSTR + ks * 32 + g16 * 8];
#pragma unroll
          for (int dt = 0; dt < 8; ++dt) {
            int d = dt * 16 + l16;
            bf16x8 vv = *(const bf16x8*)&Vs[d * 64 + (((ks * 4 + g16) ^ (d & 7)) * 8)];
#pragma unroll
            for (int mq = 0; mq < 2; ++mq)
              oacc[mq][dt] = mfma16(pa[mq], vv, oacc[mq][dt]);
          }
        }
        __builtin_amdgcn_s_setprio(0);
      }
      __syncthreads();
    }

#pragma unroll
    for (int nf = 0; nf < 2; ++nf) {
      den[nf] += __shfl_xor(den[nf], 16, 64);
      den[nf] += __shfl_xor(den[nf], 32, 64);
    }
    float rden[2][4];
#pragma unroll
    for (int mq = 0; mq < 2; ++mq)
#pragma unroll
      for (int r = 0; r < 4; ++r)
        rden[mq][r] = 1.f / __shfl(den[mq], g16 * 4 + r, 64);

#pragma unroll
    for (int mq = 0; mq < 2; ++mq)
#pragma unroll
      for (int dt = 0; dt < 8; ++dt)
#pragma unroll
        for (int r = 0; r < 4; ++r) {
          int t = q0 + mq * 16 + g16 * 4 + r;
          int d = dt * 16 + l16;
          yb[(((size_t)b * T_SEQ + t) * NH + h) * HDIM + d] = f2bf(oacc[mq][dt][r] * rden[mq][r]);
        }
    __syncthreads();
  }
}

extern "C" void kernel_launch(void* const* d_in, const int* in_sizes, int n_in,
                              void* d_out, int out_size, void* d_ws, size_t ws_size,
                              hipStream_t stream) {
  const float* x = (const float*)d_in[0];
  const float* Wq = (const float*)d_in[1];
  const float* Wk = (const float*)d_in[2];
  const float* Wv = (const float*)d_in[3];
  const float* Wproj = (const float*)d_in[4];
  const float* qg = (const float*)d_in[5];
  float* out = (float*)d_out;

  u16* xbf = (u16*)d_ws;                                   // 8192*2048
  u16* Wqkv = xbf + (size_t)8192 * 2048;                   // 3072*2048 (dead after gemm1)
  u16* Wpj = Wqkv + (size_t)3072 * 2048;                   // 2048*2048
  u16* qbuf = Wpj + (size_t)2048 * 2048;                   // 8192*2048
  u16* kbuf = qbuf + (size_t)8192 * 2048;                  // 2048*2048
  u16* vbuf = kbuf + (size_t)2048 * 2048;                  // 2048*2048
  u16* ybuf = xbf;        // alias: x dead after gemm1
  u16* vtbuf = Wqkv;      // alias: Wqkv dead after gemm1

  cvt_bf16<<<2048, 256, 0, stream>>>(x, xbf, 8192 * 2048);
  cvt_bf16<<<2048, 256, 0, stream>>>(Wq, Wqkv, 2048 * 2048);
  cvt_bf16<<<1024, 256, 0, stream>>>(Wk, Wqkv + (size_t)2048 * 2048, 512 * 2048);
  cvt_bf16<<<1024, 256, 0, stream>>>(Wv, Wqkv + (size_t)2560 * 2048, 512 * 2048);
  cvt_bf16<<<2048, 256, 0, stream>>>(Wproj, Wpj, 2048 * 2048);

  // QKV: M=8192 N=3072 -> 32x12 = 384 blocks (cpx=48)
  gemm256p4<0><<<384, 512, 0, stream>>>(xbf, Wqkv, qbuf, kbuf, vbuf, nullptr, 2048, 12, 48);

  rmsrope<<<32768, 256, 0, stream>>>(qbuf, qg, NH,
                                     1.4426950408889634f / 11.313708498984761f, 1);
  rmsrope<<<8192, 256, 0, stream>>>(kbuf, nullptr, NKV, 1.0f, 0);
  vtrans<<<dim3(32, 2, 16), 256, 0, stream>>>(vbuf, vtbuf);

  attn_fwd3<<<dim3(8, 64), 256, 0, stream>>>(qbuf, kbuf, vtbuf, ybuf, qg);

  // proj: M=8192 N=2048 -> 32x8 = 256 blocks = exactly 1 round (cpx=32)
  gemm256p4<1><<<256, 512, 0, stream>>>(ybuf, Wpj, nullptr, nullptr, nullptr, out, 2048, 8, 32);
}